// Round 1
// baseline (218.378 us; speedup 1.0000x reference)
//
#include <hip/hip_runtime.h>

#define F 128
#define NEG_SLOPE 0.2f

// One wave (64 lanes) per node: dot(x[node, :], attn[:]) over F=128 (2 floats/lane).
__global__ __launch_bounds__(256)
void node_logits_kernel(const float* __restrict__ x, const float* __restrict__ attn,
                        float* __restrict__ out, int n) {
    int gtid = blockIdx.x * blockDim.x + threadIdx.x;
    int row  = gtid >> 6;
    int lane = threadIdx.x & 63;
    if (row >= n) return;
    float2 xv = *reinterpret_cast<const float2*>(&x[(size_t)row * F + lane * 2]);
    float2 av = *reinterpret_cast<const float2*>(&attn[lane * 2]);
    float s = xv.x * av.x + xv.y * av.y;
    #pragma unroll
    for (int off = 32; off > 0; off >>= 1)
        s += __shfl_xor(s, off, 64);
    if (lane == 0) out[row] = s;
}

// One block (128 threads) per dst node; thread t owns feature t.
// dst_idx is sorted, so node v's edges are a contiguous range found by binary search.
// out[v,f] = sum_e w_e * x_src[src_e, f] / sum_e w_e, w_e = exp(leaky_relu(el[src_e]+er[v]))
__global__ __launch_bounds__(128)
void gat_aggregate_kernel(const float* __restrict__ x_src,
                          const float* __restrict__ el,
                          const float* __restrict__ er,
                          const int* __restrict__ src_idx,
                          const int* __restrict__ dst_idx,
                          float* __restrict__ out, int E, int n_dst) {
    int v   = blockIdx.x;
    int tid = threadIdx.x;

    // lower_bound(dst_idx, v)
    int lo = 0, hi = E;
    while (lo < hi) { int mid = (lo + hi) >> 1; if (dst_idx[mid] < v) lo = mid + 1; else hi = mid; }
    int start = lo;
    // lower_bound(dst_idx, v+1)
    hi = E;
    while (lo < hi) { int mid = (lo + hi) >> 1; if (dst_idx[mid] < v + 1) lo = mid + 1; else hi = mid; }
    int end = lo;

    float erv = er[v];
    float acc = 0.f;
    float den = 0.f;
    for (int e = start; e < end; ++e) {
        int s = src_idx[e];                       // broadcast load (same for all lanes)
        float logit = el[s] + erv;                // el is 200 KB -> L2 resident
        float lr = logit > 0.f ? logit : NEG_SLOPE * logit;
        float w = __expf(lr);
        den += w;
        acc += w * x_src[(size_t)s * F + tid];    // 512 B coalesced row gather
    }
    out[(size_t)v * F + tid] = (end > start) ? (acc / den) : 0.f;
}

extern "C" void kernel_launch(void* const* d_in, const int* in_sizes, int n_in,
                              void* d_out, int out_size, void* d_ws, size_t ws_size,
                              hipStream_t stream) {
    const float* x_src  = (const float*)d_in[0];
    const float* x_dst  = (const float*)d_in[1];
    const float* attn_l = (const float*)d_in[2];
    const float* attn_r = (const float*)d_in[3];
    const int*   src_idx = (const int*)d_in[4];
    const int*   dst_idx = (const int*)d_in[5];

    int n_src = in_sizes[0] / F;   // 50000
    int n_dst = in_sizes[1] / F;   // 10000
    int E     = in_sizes[4];       // 1600000

    float* out = (float*)d_out;
    float* el  = (float*)d_ws;          // n_src floats
    float* er  = el + n_src;            // n_dst floats

    // el[u] = dot(x_src[u], attn_l); er[v] = dot(x_dst[v], attn_r)
    {
        int rows_per_block = 256 / 64;  // 4 waves per block
        int blk_src = (n_src + rows_per_block - 1) / rows_per_block;
        int blk_dst = (n_dst + rows_per_block - 1) / rows_per_block;
        node_logits_kernel<<<blk_src, 256, 0, stream>>>(x_src, attn_l, el, n_src);
        node_logits_kernel<<<blk_dst, 256, 0, stream>>>(x_dst, attn_r, er, n_dst);
    }

    // fused edge-weight + segment-normalized aggregation
    gat_aggregate_kernel<<<n_dst, 128, 0, stream>>>(x_src, el, er, src_idx, dst_idx,
                                                    out, E, n_dst);
}

// Round 2
// 116.459 us; speedup vs baseline: 1.8752x; 1.8752x over previous
//
#include <hip/hip_runtime.h>

#define F 128
#define NEG_SLOPE 0.2f
#define NG 8           // edge groups per block
#define GSZ 32         // lanes per group: 32 x float4 = 128 features

// One wave (64 lanes) per node: dot(x[node, :], attn[:]) over F=128 (2 floats/lane).
__global__ __launch_bounds__(256)
void node_logits_kernel(const float* __restrict__ x, const float* __restrict__ attn,
                        float* __restrict__ out, int n) {
    int gtid = blockIdx.x * blockDim.x + threadIdx.x;
    int row  = gtid >> 6;
    int lane = threadIdx.x & 63;
    if (row >= n) return;
    float2 xv = *reinterpret_cast<const float2*>(&x[(size_t)row * F + lane * 2]);
    float2 av = *reinterpret_cast<const float2*>(&attn[lane * 2]);
    float s = xv.x * av.x + xv.y * av.y;
    #pragma unroll
    for (int off = 32; off > 0; off >>= 1)
        s += __shfl_xor(s, off, 64);
    if (lane == 0) out[row] = s;
}

// dst_idx is sorted: build CSR row offsets (offs[v] = first edge of node v, offs[n_dst] = E).
__global__ __launch_bounds__(256)
void build_offsets_kernel(const int* __restrict__ dst_idx, int* __restrict__ offs,
                          int E, int n_dst) {
    int e = blockIdx.x * blockDim.x + threadIdx.x;
    if (e >= E) return;
    int d = dst_idx[e];
    int prev = (e == 0) ? -1 : dst_idx[e - 1];
    for (int v = prev + 1; v <= d; ++v) offs[v] = e;
    if (e == E - 1)
        for (int v = d + 1; v <= n_dst; ++v) offs[v] = E;
}

// One block (256 threads) per dst node. 8 groups of 32 lanes; each group handles
// one edge per step (x2 unrolled -> 16 edge-row gathers in flight). Lane owns
// 4 features (float4). Per-group partial numerator/denominator merged in LDS.
__global__ __launch_bounds__(NG * GSZ)
void gat_aggregate_kernel(const float* __restrict__ x_src,
                          const float* __restrict__ el,
                          const float* __restrict__ er,
                          const int* __restrict__ src_idx,
                          const int* __restrict__ offs,
                          float* __restrict__ out) {
    int v    = blockIdx.x;
    int tid  = threadIdx.x;
    int g    = tid >> 5;
    int lane = tid & 31;

    int start = offs[v];
    int end   = offs[v + 1];
    int count = end - start;
    float erv = er[v];

    const float4* xs4 = reinterpret_cast<const float4*>(x_src);

    float4 a0 = make_float4(0.f, 0.f, 0.f, 0.f);
    float4 a1 = make_float4(0.f, 0.f, 0.f, 0.f);
    float  d0 = 0.f, d1 = 0.f;

    int full = count & ~(2 * NG - 1);   // multiple of 16
    for (int it = 0; it < full; it += 2 * NG) {
        int e0 = start + it + g;
        int e1 = e0 + NG;
        int s0 = src_idx[e0];           // broadcast within group
        int s1 = src_idx[e1];
        float l0 = el[s0] + erv;
        float l1 = el[s1] + erv;
        l0 = l0 > 0.f ? l0 : NEG_SLOPE * l0;
        l1 = l1 > 0.f ? l1 : NEG_SLOPE * l1;
        float w0 = __expf(l0);
        float w1 = __expf(l1);
        float4 x0 = xs4[(size_t)s0 * (F / 4) + lane];
        float4 x1 = xs4[(size_t)s1 * (F / 4) + lane];
        d0 += w0;  d1 += w1;
        a0.x += w0 * x0.x; a0.y += w0 * x0.y; a0.z += w0 * x0.z; a0.w += w0 * x0.w;
        a1.x += w1 * x1.x; a1.y += w1 * x1.y; a1.z += w1 * x1.z; a1.w += w1 * x1.w;
    }
    // tail: stride-NG, one edge per group
    for (int e = start + full + g; e < end; e += NG) {
        int s = src_idx[e];
        float l = el[s] + erv;
        l = l > 0.f ? l : NEG_SLOPE * l;
        float w = __expf(l);
        float4 x = xs4[(size_t)s * (F / 4) + lane];
        d0 += w;
        a0.x += w * x.x; a0.y += w * x.y; a0.z += w * x.z; a0.w += w * x.w;
    }
    a0.x += a1.x; a0.y += a1.y; a0.z += a1.z; a0.w += a1.w;
    d0 += d1;

    __shared__ float4 lacc[NG][GSZ];
    __shared__ float  lden[NG];
    lacc[g][lane] = a0;
    if (lane == 0) lden[g] = d0;
    __syncthreads();

    if (g == 0) {
        float4 t  = lacc[0][lane];
        float  dd = lden[0];
        #pragma unroll
        for (int k = 1; k < NG; ++k) {
            float4 u = lacc[k][lane];
            t.x += u.x; t.y += u.y; t.z += u.z; t.w += u.w;
            dd += lden[k];
        }
        float inv = (count > 0) ? 1.f / dd : 0.f;
        float4 o = make_float4(t.x * inv, t.y * inv, t.z * inv, t.w * inv);
        reinterpret_cast<float4*>(out)[(size_t)v * (F / 4) + lane] = o;
    }
}

extern "C" void kernel_launch(void* const* d_in, const int* in_sizes, int n_in,
                              void* d_out, int out_size, void* d_ws, size_t ws_size,
                              hipStream_t stream) {
    const float* x_src   = (const float*)d_in[0];
    const float* x_dst   = (const float*)d_in[1];
    const float* attn_l  = (const float*)d_in[2];
    const float* attn_r  = (const float*)d_in[3];
    const int*   src_idx = (const int*)d_in[4];
    const int*   dst_idx = (const int*)d_in[5];

    int n_src = in_sizes[0] / F;   // 50000
    int n_dst = in_sizes[1] / F;   // 10000
    int E     = in_sizes[4];       // 1600000

    float* out  = (float*)d_out;
    float* el   = (float*)d_ws;                 // n_src floats
    float* er   = el + n_src;                   // n_dst floats
    int*   offs = (int*)(er + n_dst);           // n_dst+1 ints

    {
        int rows_per_block = 256 / 64;  // 4 waves per block
        int blk_src = (n_src + rows_per_block - 1) / rows_per_block;
        int blk_dst = (n_dst + rows_per_block - 1) / rows_per_block;
        node_logits_kernel<<<blk_src, 256, 0, stream>>>(x_src, attn_l, el, n_src);
        node_logits_kernel<<<blk_dst, 256, 0, stream>>>(x_dst, attn_r, er, n_dst);
    }
    build_offsets_kernel<<<(E + 255) / 256, 256, 0, stream>>>(dst_idx, offs, E, n_dst);

    gat_aggregate_kernel<<<n_dst, NG * GSZ, 0, stream>>>(x_src, el, er, src_idx, offs, out);
}